// Round 5
// baseline (298.051 us; speedup 1.0000x reference)
//
#include <hip/hip_runtime.h>

#define NT 1024      // N_TOPICS
#define TD 128       // TOPIC_DIM
#define HID 512      // HIDDEN
#define NH 8         // N_HEADS
#define HD 64        // HEAD_DIM
#define NB 8         // BATCH

typedef unsigned short us;
typedef short bf16x8 __attribute__((ext_vector_type(8)));
typedef float f32x4 __attribute__((ext_vector_type(4)));

__device__ __forceinline__ us f2bf(float x) {
    unsigned int u = __float_as_uint(x);
    return (us)((u + 0x7FFFu + ((u >> 16) & 1u)) >> 16);
}
__device__ __forceinline__ float bf2f(us s) {
    return __uint_as_float(((unsigned int)s) << 16);
}

// ============ kprep: kmax1 (blocks 0-1023) | knode0 (1024-2047) | kcvt (2048-2175) ======
__global__ __launch_bounds__(256) void kprep(const float* __restrict__ tm, float* __restrict__ part,
                                             const float* __restrict__ emb, const float* __restrict__ sW,
                                             const float* __restrict__ sb, us* __restrict__ node0b,
                                             const float* __restrict__ gW, us* __restrict__ Wt) {
    int bx = blockIdx.x, t = threadIdx.x;
    if (bx < 1024) {
        __shared__ float red[256];
        float m = -1e30f;
        for (size_t i = (size_t)bx * 256 + t; i < (size_t)NB * NT * NT; i += 1024 * 256) m = fmaxf(m, tm[i]);
        red[t] = m; __syncthreads();
        for (int s = 128; s > 0; s >>= 1) { if (t < s) red[t] = fmaxf(red[t], red[t + s]); __syncthreads(); }
        if (t == 0) part[bx] = red[0];
    } else if (bx < 2048) {
        int n = bx - 1024;
        __shared__ float er[TD];
        if (t < TD) er[t] = emb[n * TD + t];
        __syncthreads();
        for (int k = t; k < HID; k += 256) {
            const float4* w = (const float4*)(sW + (size_t)k * TD);
            float acc = 0.f;
            #pragma unroll
            for (int i = 0; i < TD / 4; i++) {
                float4 wv = w[i];
                float4 ev = *(const float4*)(er + i * 4);
                acc += wv.x * ev.x + wv.y * ev.y + wv.z * ev.z + wv.w * ev.w;
            }
            node0b[(size_t)n * HID + k] = f2bf(acc + sb[k]);
        }
    } else {
        int g = bx - 2048; int lh = g >> 3, seg = g & 7;
        const float* src = gW + (size_t)lh * HID * HD;
        us* dst = Wt + (size_t)lh * HD * HID;
        for (int idx = seg * 4096 + t; idx < (seg + 1) * 4096; idx += 256) {
            int k = idx >> 6, o = idx & 63;
            dst[o * HID + k] = f2bf(src[idx]);
        }
    }
}

// ============ shared GEMM body: 64x64 tile, BK=64, double-buffered, 1 barrier/iter ======
// A: [b*NT+i][HID] bf16; W: [(h*64+o)][HID] bf16. Fused e_src/e_dst epilogue.
__device__ __forceinline__ void gemm_body(const us* __restrict__ A, const us* __restrict__ W,
                                          const float* __restrict__ gav,
                                          us* __restrict__ outT, us* __restrict__ outR,
                                          float* __restrict__ esO, float* __restrict__ edO,
                                          int iblk, int b, int h, int t, us* sm) {
    us* As = sm;              // [2][64*72]
    us* Bs = sm + 2 * 4608;   // [2][64*72]
    int row = t >> 2, ks = t & 3;
    int l = t & 63, w = t >> 6, m = l & 15, q = l >> 4;
    size_t arow0 = (size_t)(b * NT + iblk * 64);
    const us* ar = A + (arow0 + row) * HID + ks * 16;
    const us* br = W + ((size_t)(h * HD + row)) * HID + ks * 16;
    f32x4 acc[4];
    #pragma unroll
    for (int ot = 0; ot < 4; ot++) acc[ot] = (f32x4){0.f, 0.f, 0.f, 0.f};
    {   // prologue: stage k-tile 0 into buf 0
        uint4 a0 = *(const uint4*)ar, a1 = *(const uint4*)(ar + 8);
        uint4 b0 = *(const uint4*)br, b1 = *(const uint4*)(br + 8);
        *(uint4*)&As[row * 72 + ks * 16] = a0; *(uint4*)&As[row * 72 + ks * 16 + 8] = a1;
        *(uint4*)&Bs[row * 72 + ks * 16] = b0; *(uint4*)&Bs[row * 72 + ks * 16 + 8] = b1;
    }
    for (int it = 0; it < 8; it++) {
        int cur = it & 1, nxt = cur ^ 1;
        uint4 a0, a1, b0, b1;
        if (it < 7) {
            int k0 = (it + 1) * 64;
            a0 = *(const uint4*)(ar + k0); a1 = *(const uint4*)(ar + k0 + 8);
            b0 = *(const uint4*)(br + k0); b1 = *(const uint4*)(br + k0 + 8);
        }
        __syncthreads();
        if (it < 7) {
            *(uint4*)&As[nxt * 4608 + row * 72 + ks * 16] = a0;
            *(uint4*)&As[nxt * 4608 + row * 72 + ks * 16 + 8] = a1;
            *(uint4*)&Bs[nxt * 4608 + row * 72 + ks * 16] = b0;
            *(uint4*)&Bs[nxt * 4608 + row * 72 + ks * 16 + 8] = b1;
        }
        const us* Ac = As + cur * 4608; const us* Bc = Bs + cur * 4608;
        #pragma unroll
        for (int kt = 0; kt < 2; kt++) {
            bf16x8 av = *(const bf16x8*)&Ac[(w * 16 + m) * 72 + kt * 32 + q * 8];
            #pragma unroll
            for (int ot = 0; ot < 4; ot++) {
                bf16x8 bv = *(const bf16x8*)&Bc[(ot * 16 + m) * 72 + kt * 32 + q * 8];
                acc[ot] = __builtin_amdgcn_mfma_f32_16x16x32_bf16(av, bv, acc[ot], 0, 0, 0);
            }
        }
    }
    // fused e_src/e_dst epilogue
    const float* gas = gav + h * 2 * HD;
    float gs[4], gd[4];
    #pragma unroll
    for (int ot = 0; ot < 4; ot++) { gs[ot] = gas[ot * 16 + m]; gd[ot] = gas[HD + ot * 16 + m]; }
    size_t ebase = ((size_t)b * NH + h) * NT + iblk * 64;
    #pragma unroll
    for (int rr = 0; rr < 4; rr++) {
        float s = 0.f, d = 0.f;
        #pragma unroll
        for (int ot = 0; ot < 4; ot++) { float v = acc[ot][rr]; s = fmaf(v, gs[ot], s); d = fmaf(v, gd[ot], d); }
        #pragma unroll
        for (int mask = 1; mask < 16; mask <<= 1) { s += __shfl_xor(s, mask); d += __shfl_xor(d, mask); }
        if (m == 0) {
            int rowi = w * 16 + q * 4 + rr;
            esO[ebase + rowi] = s;
            edO[ebase + rowi] = d;
        }
    }
    #pragma unroll
    for (int ot = 0; ot < 4; ot++) {
        int col = h * HD + ot * 16 + m;
        #pragma unroll
        for (int rr = 0; rr < 4; rr++) {
            int i_loc = w * 16 + q * 4 + rr;
            float v = acc[ot][rr];
            if (outT) outT[(size_t)col * NT + iblk * 64 + i_loc] = f2bf(v);
            if (outR) outR[(arow0 + i_loc) * HID + col] = f2bf(v);
        }
    }
}

// ============ kphase1: ktw (blocks 0-2047) | layer-1 GEMM (2048-2175) ====================
__global__ __launch_bounds__(256) void kphase1(const float* __restrict__ tm, const int* __restrict__ adj,
                                               const float* __restrict__ part, us* __restrict__ TWb,
                                               const us* __restrict__ node0b, const us* __restrict__ Wt,
                                               const float* __restrict__ ga, us* __restrict__ Ht1,
                                               float* __restrict__ es1, float* __restrict__ ed1) {
    __shared__ __align__(16) us sm[4 * 4608];
    int bx = blockIdx.x, t = threadIdx.x;
    if (bx < 2048) {
        float* red = (float*)sm;
        float m = fmaxf(fmaxf(part[t * 4], part[t * 4 + 1]), fmaxf(part[t * 4 + 2], part[t * 4 + 3]));
        red[t] = m; __syncthreads();
        for (int s = 128; s > 0; s >>= 1) { if (t < s) red[t] = fmaxf(red[t], red[t + s]); __syncthreads(); }
        float tmx = red[0];
        #pragma unroll
        for (int it = 0; it < 4; it++) {
            size_t idx = (((size_t)bx * 4 + it) * 256 + t) * 4;
            float4 tv = *(const float4*)(tm + idx);
            int4 av = *(const int4*)(adj + idx);
            unsigned int r0 = av.x ? f2bf(__expf(0.1f * (tv.x - tmx))) : 0u;
            unsigned int r1 = av.y ? f2bf(__expf(0.1f * (tv.y - tmx))) : 0u;
            unsigned int r2 = av.z ? f2bf(__expf(0.1f * (tv.z - tmx))) : 0u;
            unsigned int r3 = av.w ? f2bf(__expf(0.1f * (tv.w - tmx))) : 0u;
            uint2 pk; pk.x = r0 | (r1 << 16); pk.y = r2 | (r3 << 16);
            *(uint2*)&TWb[idx] = pk;
        }
    } else {
        int g = bx - 2048;
        gemm_body(node0b, Wt, ga, Ht1, nullptr, es1, ed1, g & 15, 0, g >> 4, t, sm);
    }
}

// ============ layer-2 GEMM =============================================================
__global__ __launch_bounds__(256) void kgemm2(const us* __restrict__ node1b, const us* __restrict__ Wt2,
                                              const float* __restrict__ ga2, us* __restrict__ H2b,
                                              float* __restrict__ es2, float* __restrict__ ed2) {
    __shared__ __align__(16) us sm[4 * 4608];
    int x = blockIdx.x;
    gemm_body(node1b, Wt2, ga2, nullptr, H2b, es2, ed2, x & 15, x >> 4, blockIdx.y, threadIdx.x, sm);
}

// ============ layer-1 fused attention: BK=64, double-buffered, perm-packed P ============
__device__ __forceinline__ void p_tile(const us* __restrict__ twp, const float* __restrict__ edp,
                                       const us* __restrict__ htp, float es_i, float& lp,
                                       uint4& P0, uint4& P1, uint4& H0, uint4& H1) {
    union { uint4 v; us u[8]; } tw0, tw1;
    tw0.v = *(const uint4*)twp;
    tw1.v = *(const uint4*)(twp + 8);
    H0 = *(const uint4*)htp;
    H1 = *(const uint4*)(htp + 8);
    float ev[16];
    *(float4*)&ev[0]  = *(const float4*)edp;
    *(float4*)&ev[4]  = *(const float4*)(edp + 4);
    *(float4*)&ev[8]  = *(const float4*)(edp + 8);
    *(float4*)&ev[12] = *(const float4*)(edp + 12);
    unsigned int pk[8];
    #pragma unroll
    for (int r = 0; r < 4; r++) {
        float twa = bf2f(tw0.u[2 * r]), twb = bf2f(tw0.u[2 * r + 1]);
        float ea = es_i + ev[2 * r];     ea = fmaxf(ea, 0.2f * ea) * twa;
        float pa = tw0.u[2 * r] ? __expf(ea) : 0.f;
        float eb = es_i + ev[2 * r + 1]; eb = fmaxf(eb, 0.2f * eb) * twb;
        float pb = tw0.u[2 * r + 1] ? __expf(eb) : 0.f;
        // truncate-to-bf16 pack (1 perm); denominator sums the SAME truncated values
        lp += __uint_as_float(__float_as_uint(pa) & 0xFFFF0000u)
            + __uint_as_float(__float_as_uint(pb) & 0xFFFF0000u);
        pk[r] = __builtin_amdgcn_perm(__float_as_uint(pb), __float_as_uint(pa), 0x07060302);
    }
    #pragma unroll
    for (int r = 0; r < 4; r++) {
        float twa = bf2f(tw1.u[2 * r]), twb = bf2f(tw1.u[2 * r + 1]);
        float ea = es_i + ev[8 + 2 * r];     ea = fmaxf(ea, 0.2f * ea) * twa;
        float pa = tw1.u[2 * r] ? __expf(ea) : 0.f;
        float eb = es_i + ev[8 + 2 * r + 1]; eb = fmaxf(eb, 0.2f * eb) * twb;
        float pb = tw1.u[2 * r + 1] ? __expf(eb) : 0.f;
        lp += __uint_as_float(__float_as_uint(pa) & 0xFFFF0000u)
            + __uint_as_float(__float_as_uint(pb) & 0xFFFF0000u);
        pk[4 + r] = __builtin_amdgcn_perm(__float_as_uint(pb), __float_as_uint(pa), 0x07060302);
    }
    P0 = make_uint4(pk[0], pk[1], pk[2], pk[3]);
    P1 = make_uint4(pk[4], pk[5], pk[6], pk[7]);
}

__global__ __launch_bounds__(256) void kattn1(const us* __restrict__ TWb, const us* __restrict__ Ht,
                                              const float* __restrict__ es, const float* __restrict__ ed,
                                              us* __restrict__ node1b) {
    int x = blockIdx.x; int iblk = x & 15; int b = x >> 4; int h = blockIdx.y;
    int t = threadIdx.x;
    __shared__ __align__(16) us Ps[2 * 4608];
    __shared__ __align__(16) us Hs[2 * 4608];
    __shared__ float Ls[64 * 5];
    __shared__ float invl_s[64];
    int i = t >> 2, js = t & 3;
    int l = t & 63, w = t >> 6, m = l & 15, q = l >> 4;
    float es_i = es[h * NT + iblk * 64 + i];
    const us* twrow = TWb + ((size_t)(b * NT) + iblk * 64 + i) * NT + js * 16;
    const float* edh = ed + h * NT + js * 16;
    const us* htrow = Ht + ((size_t)(h * HD) + i) * NT + js * 16;
    f32x4 acc[4];
    #pragma unroll
    for (int ot = 0; ot < 4; ot++) acc[ot] = (f32x4){0.f, 0.f, 0.f, 0.f};
    float lp = 0.f;
    uint4 P0, P1, H0, H1;
    // prologue: stage j-tile 0 into buf 0
    p_tile(twrow, edh, htrow, es_i, lp, P0, P1, H0, H1);
    {
        us* Pd = Ps + i * 72 + js * 16;
        us* Hd = Hs + i * 72 + js * 16;
        *(uint4*)Pd = P0; *(uint4*)(Pd + 8) = P1;
        *(uint4*)Hd = H0; *(uint4*)(Hd + 8) = H1;
    }
    for (int it = 0; it < 16; it++) {
        int cur = it & 1;
        if (it < 15) {
            int j0 = (it + 1) * 64;
            p_tile(twrow + j0, edh + j0, htrow + j0, es_i, lp, P0, P1, H0, H1);
        }
        __syncthreads();
        if (it < 15) {
            int nxt = cur ^ 1;
            us* Pd = Ps + nxt * 4608 + i * 72 + js * 16;
            us* Hd = Hs + nxt * 4608 + i * 72 + js * 16;
            *(uint4*)Pd = P0; *(uint4*)(Pd + 8) = P1;
            *(uint4*)Hd = H0; *(uint4*)(Hd + 8) = H1;
        }
        const us* Pc = Ps + cur * 4608; const us* Hc = Hs + cur * 4608;
        #pragma unroll
        for (int kt = 0; kt < 2; kt++) {
            bf16x8 av = *(const bf16x8*)&Pc[(w * 16 + m) * 72 + kt * 32 + q * 8];
            #pragma unroll
            for (int ot = 0; ot < 4; ot++) {
                bf16x8 bv = *(const bf16x8*)&Hc[(ot * 16 + m) * 72 + kt * 32 + q * 8];
                acc[ot] = __builtin_amdgcn_mfma_f32_16x16x32_bf16(av, bv, acc[ot], 0, 0, 0);
            }
        }
    }
    Ls[i * 5 + js] = lp;
    __syncthreads();
    if (t < 64) {
        float s = Ls[t * 5] + Ls[t * 5 + 1] + Ls[t * 5 + 2] + Ls[t * 5 + 3];
        invl_s[t] = 1.f / s;
    }
    __syncthreads();
    #pragma unroll
    for (int ot = 0; ot < 4; ot++) {
        int col = h * HD + ot * 16 + m;
        #pragma unroll
        for (int rr = 0; rr < 4; rr++) {
            int i_loc = w * 16 + q * 4 + rr;
            float v = acc[ot][rr] * invl_s[i_loc];
            v = v > 0.f ? v : (__expf(v) - 1.f);  // ELU
            node1b[(size_t)(b * NT + iblk * 64 + i_loc) * HID + col] = f2bf(v);
        }
    }
}

// ============ layer-2 attention (8 rows) + final MLP, one block per batch ==============
__global__ __launch_bounds__(512) void kattn2h(const us* __restrict__ TWb, const us* __restrict__ H2b,
                                               const float* __restrict__ es2, const float* __restrict__ ed2,
                                               const int* __restrict__ topic_ids, const float* __restrict__ attr,
                                               const float* __restrict__ aW, const float* __restrict__ ab,
                                               const float* __restrict__ fc1W, const float* __restrict__ fc1b,
                                               const float* __restrict__ fc2W, const float* __restrict__ fc2b,
                                               float* __restrict__ out) {
    int b = blockIdx.x, t = threadIdx.x;
    __shared__ float pls[NT];
    __shared__ float red[2048];
    __shared__ float feat_s[HID];
    __shared__ float linv_s;
    int qi = topic_ids[b];
    const us* twrow = TWb + ((size_t)(b * NT) + qi) * NT;
    int og = t & 15, seg = t >> 4;   // o = og*4..+3, 32 j per seg
    for (int h = 0; h < NH; h++) {
        float esq = es2[((size_t)b * NH + h) * NT + qi];
        const float* edh = ed2 + ((size_t)b * NH + h) * NT;
        float lsum = 0.f;
        #pragma unroll
        for (int rep = 0; rep < 2; rep++) {
            int j = t + rep * 512;
            us twu = twrow[j];
            float tw = bf2f(twu);
            float e = esq + edh[j];
            e = fmaxf(e, 0.2f * e) * tw;
            float p = twu ? __expf(e) : 0.f;
            pls[j] = p; lsum += p;
        }
        red[t] = lsum; __syncthreads();
        for (int s = 256; s > 0; s >>= 1) { if (t < s) red[t] += red[t + s]; __syncthreads(); }
        if (t == 0) linv_s = 1.f / red[0];
        __syncthreads();
        float a0 = 0.f, a1 = 0.f, a2 = 0.f, a3 = 0.f;
        const us* hb = H2b + ((size_t)(b * NT) + seg * 32) * HID + h * HD + og * 4;
        #pragma unroll 8
        for (int jj = 0; jj < 32; jj++) {
            float p = pls[seg * 32 + jj];
            uint2 hv = *(const uint2*)(hb + (size_t)jj * HID);
            a0 = fmaf(p, __uint_as_float(hv.x << 16), a0);
            a1 = fmaf(p, __uint_as_float(hv.x & 0xFFFF0000u), a1);
            a2 = fmaf(p, __uint_as_float(hv.y << 16), a2);
            a3 = fmaf(p, __uint_as_float(hv.y & 0xFFFF0000u), a3);
        }
        red[(og * 4 + 0) * 32 + seg] = a0;
        red[(og * 4 + 1) * 32 + seg] = a1;
        red[(og * 4 + 2) * 32 + seg] = a2;
        red[(og * 4 + 3) * 32 + seg] = a3;
        __syncthreads();
        if (t < 64) {
            float s = 0.f;
            #pragma unroll
            for (int sg = 0; sg < 32; sg++) s += red[t * 32 + sg];
            float v = s * linv_s;
            v = v > 0.f ? v : (__expf(v) - 1.f);  // ELU
            feat_s[h * HD + t] = v;
        }
        __syncthreads();
    }
    // final MLP (512 threads, one output row each)
    float av = attr[b];
    pls[t] = feat_s[t] + av * aW[t] + ab[t];   // comb, reuse pls
    __syncthreads();
    const float4* wr = (const float4*)(fc1W + (size_t)t * HID);
    float acc = 0.f;
    #pragma unroll 4
    for (int mm = 0; mm < HID / 4; mm++) {
        float4 w4 = wr[mm];
        float4 c4 = *(const float4*)(pls + mm * 4);
        acc += w4.x * c4.x + w4.y * c4.y + w4.z * c4.z + w4.w * c4.w;
    }
    float hk = fmaxf(acc + fc1b[t], 0.f);
    red[t] = hk * fc2W[t];
    __syncthreads();
    for (int s = 256; s > 0; s >>= 1) { if (t < s) red[t] += red[t + s]; __syncthreads(); }
    if (t == 0) out[b] = red[0] + fc2b[0];
}

extern "C" void kernel_launch(void* const* d_in, const int* in_sizes, int n_in,
                              void* d_out, int out_size, void* d_ws, size_t ws_size,
                              hipStream_t stream) {
    const int*   topic_ids = (const int*)d_in[0];
    const int*   adj       = (const int*)d_in[1];
    const float* tm        = (const float*)d_in[2];
    const float* attr      = (const float*)d_in[3];
    const float* emb       = (const float*)d_in[4];
    const float* sW        = (const float*)d_in[5];
    const float* sb        = (const float*)d_in[6];
    const float* aW        = (const float*)d_in[7];
    const float* ab        = (const float*)d_in[8];
    const float* gW        = (const float*)d_in[9];   // (2,8,512,64)
    const float* ga        = (const float*)d_in[10];  // (2,8,128,1)
    const float* fc1W      = (const float*)d_in[11];
    const float* fc1b      = (const float*)d_in[12];
    const float* fc2W      = (const float*)d_in[13];
    const float* fc2b      = (const float*)d_in[14];
    float* out = (float*)d_out;

    char* p = (char*)d_ws;
    us* TWb    = (us*)p; p += sizeof(us) * (size_t)NB * NT * NT;        // 16.8 MB
    us* node0b = (us*)p; p += sizeof(us) * (size_t)NT * HID;            // 1 MB
    us* Wt     = (us*)p; p += sizeof(us) * (size_t)2 * NH * HD * HID;   // 1 MB
    us* Ht1    = (us*)p; p += sizeof(us) * (size_t)HID * NT;            // 1 MB
    us* node1b = (us*)p; p += sizeof(us) * (size_t)NB * NT * HID;       // 8 MB
    us* H2b    = (us*)p; p += sizeof(us) * (size_t)NB * NT * HID;       // 8 MB
    float* es1  = (float*)p; p += sizeof(float) * NH * NT;
    float* ed1  = (float*)p; p += sizeof(float) * NH * NT;
    float* es2  = (float*)p; p += sizeof(float) * NB * NH * NT;
    float* ed2  = (float*)p; p += sizeof(float) * NB * NH * NT;
    float* part = (float*)p; p += sizeof(float) * 1024;

    kprep<<<2176, 256, 0, stream>>>(tm, part, emb, sW, sb, node0b, gW, Wt);
    kphase1<<<2176, 256, 0, stream>>>(tm, adj, part, TWb, node0b, Wt, ga, Ht1, es1, ed1);
    kattn1<<<dim3(16 * NB, NH), 256, 0, stream>>>(TWb, Ht1, es1, ed1, node1b);
    kgemm2<<<dim3(16 * NB, NH), 256, 0, stream>>>(node1b, Wt + (size_t)NH * HD * HID,
                                                  ga + NH * 2 * HD, H2b, es2, ed2);
    kattn2h<<<NB, 512, 0, stream>>>(TWb, H2b, es2, ed2, topic_ids, attr, aW, ab,
                                    fc1W, fc1b, fc2W, fc2b, out);
}

// Round 6
// 268.575 us; speedup vs baseline: 1.1097x; 1.1097x over previous
//
#include <hip/hip_runtime.h>

#define NT 1024      // N_TOPICS
#define TD 128       // TOPIC_DIM
#define HID 512      // HIDDEN
#define NH 8         // N_HEADS
#define HD 64        // HEAD_DIM
#define NB 8         // BATCH

typedef unsigned short us;
typedef short bf16x8 __attribute__((ext_vector_type(8)));
typedef float f32x4 __attribute__((ext_vector_type(4)));

__device__ __forceinline__ us f2bf(float x) {
    unsigned int u = __float_as_uint(x);
    return (us)((u + 0x7FFFu + ((u >> 16) & 1u)) >> 16);
}
__device__ __forceinline__ float bf2f(us s) {
    return __uint_as_float(((unsigned int)s) << 16);
}

// ============ kprep: kmax1 (blocks 0-1023) | knode0 (1024-2047) | kcvt (2048-2175) ======
__global__ __launch_bounds__(256) void kprep(const float* __restrict__ tm, float* __restrict__ part,
                                             const float* __restrict__ emb, const float* __restrict__ sW,
                                             const float* __restrict__ sb, us* __restrict__ node0b,
                                             const float* __restrict__ gW, us* __restrict__ Wt) {
    int bx = blockIdx.x, t = threadIdx.x;
    if (bx < 1024) {
        __shared__ float red[256];
        float m = -1e30f;
        for (size_t i = (size_t)bx * 256 + t; i < (size_t)NB * NT * NT; i += 1024 * 256) m = fmaxf(m, tm[i]);
        red[t] = m; __syncthreads();
        for (int s = 128; s > 0; s >>= 1) { if (t < s) red[t] = fmaxf(red[t], red[t + s]); __syncthreads(); }
        if (t == 0) part[bx] = red[0];
    } else if (bx < 2048) {
        int n = bx - 1024;
        __shared__ float er[TD];
        if (t < TD) er[t] = emb[n * TD + t];
        __syncthreads();
        for (int k = t; k < HID; k += 256) {
            const float4* w = (const float4*)(sW + (size_t)k * TD);
            float acc = 0.f;
            #pragma unroll
            for (int i = 0; i < TD / 4; i++) {
                float4 wv = w[i];
                float4 ev = *(const float4*)(er + i * 4);
                acc += wv.x * ev.x + wv.y * ev.y + wv.z * ev.z + wv.w * ev.w;
            }
            node0b[(size_t)n * HID + k] = f2bf(acc + sb[k]);
        }
    } else {
        int g = bx - 2048; int lh = g >> 3, seg = g & 7;
        const float* src = gW + (size_t)lh * HID * HD;
        us* dst = Wt + (size_t)lh * HD * HID;
        for (int idx = seg * 4096 + t; idx < (seg + 1) * 4096; idx += 256) {
            int k = idx >> 6, o = idx & 63;
            dst[o * HID + k] = f2bf(src[idx]);
        }
    }
}

// ============ shared GEMM body: 64x64 tile, BK=64, double-buffered, 1 barrier/iter ======
__device__ __forceinline__ void gemm_body(const us* __restrict__ A, const us* __restrict__ W,
                                          const float* __restrict__ gav,
                                          us* __restrict__ outT, us* __restrict__ outR,
                                          float* __restrict__ esO, float* __restrict__ edO,
                                          int iblk, int b, int h, int t, us* sm) {
    us* As = sm;              // [2][64*72]
    us* Bs = sm + 2 * 4608;   // [2][64*72]
    int row = t >> 2, ks = t & 3;
    int l = t & 63, w = t >> 6, m = l & 15, q = l >> 4;
    size_t arow0 = (size_t)(b * NT + iblk * 64);
    const us* ar = A + (arow0 + row) * HID + ks * 16;
    const us* br = W + ((size_t)(h * HD + row)) * HID + ks * 16;
    f32x4 acc[4];
    #pragma unroll
    for (int ot = 0; ot < 4; ot++) acc[ot] = (f32x4){0.f, 0.f, 0.f, 0.f};
    {
        uint4 a0 = *(const uint4*)ar, a1 = *(const uint4*)(ar + 8);
        uint4 b0 = *(const uint4*)br, b1 = *(const uint4*)(br + 8);
        *(uint4*)&As[row * 72 + ks * 16] = a0; *(uint4*)&As[row * 72 + ks * 16 + 8] = a1;
        *(uint4*)&Bs[row * 72 + ks * 16] = b0; *(uint4*)&Bs[row * 72 + ks * 16 + 8] = b1;
    }
    for (int it = 0; it < 8; it++) {
        int cur = it & 1, nxt = cur ^ 1;
        uint4 a0, a1, b0, b1;
        if (it < 7) {
            int k0 = (it + 1) * 64;
            a0 = *(const uint4*)(ar + k0); a1 = *(const uint4*)(ar + k0 + 8);
            b0 = *(const uint4*)(br + k0); b1 = *(const uint4*)(br + k0 + 8);
        }
        __syncthreads();
        if (it < 7) {
            *(uint4*)&As[nxt * 4608 + row * 72 + ks * 16] = a0;
            *(uint4*)&As[nxt * 4608 + row * 72 + ks * 16 + 8] = a1;
            *(uint4*)&Bs[nxt * 4608 + row * 72 + ks * 16] = b0;
            *(uint4*)&Bs[nxt * 4608 + row * 72 + ks * 16 + 8] = b1;
        }
        const us* Ac = As + cur * 4608; const us* Bc = Bs + cur * 4608;
        #pragma unroll
        for (int kt = 0; kt < 2; kt++) {
            bf16x8 av = *(const bf16x8*)&Ac[(w * 16 + m) * 72 + kt * 32 + q * 8];
            #pragma unroll
            for (int ot = 0; ot < 4; ot++) {
                bf16x8 bv = *(const bf16x8*)&Bc[(ot * 16 + m) * 72 + kt * 32 + q * 8];
                acc[ot] = __builtin_amdgcn_mfma_f32_16x16x32_bf16(av, bv, acc[ot], 0, 0, 0);
            }
        }
    }
    const float* gas = gav + h * 2 * HD;
    float gs[4], gd[4];
    #pragma unroll
    for (int ot = 0; ot < 4; ot++) { gs[ot] = gas[ot * 16 + m]; gd[ot] = gas[HD + ot * 16 + m]; }
    size_t ebase = ((size_t)b * NH + h) * NT + iblk * 64;
    #pragma unroll
    for (int rr = 0; rr < 4; rr++) {
        float s = 0.f, d = 0.f;
        #pragma unroll
        for (int ot = 0; ot < 4; ot++) { float v = acc[ot][rr]; s = fmaf(v, gs[ot], s); d = fmaf(v, gd[ot], d); }
        #pragma unroll
        for (int mask = 1; mask < 16; mask <<= 1) { s += __shfl_xor(s, mask); d += __shfl_xor(d, mask); }
        if (m == 0) {
            int rowi = w * 16 + q * 4 + rr;
            esO[ebase + rowi] = s;
            edO[ebase + rowi] = d;
        }
    }
    #pragma unroll
    for (int ot = 0; ot < 4; ot++) {
        int col = h * HD + ot * 16 + m;
        #pragma unroll
        for (int rr = 0; rr < 4; rr++) {
            int i_loc = w * 16 + q * 4 + rr;
            float v = acc[ot][rr];
            if (outT) outT[(size_t)col * NT + iblk * 64 + i_loc] = f2bf(v);
            if (outR) outR[(arow0 + i_loc) * HID + col] = f2bf(v);
        }
    }
}

// ============ kphase1: ktw (blocks 0-2047) | layer-1 GEMM (2048-2175) ====================
__global__ __launch_bounds__(256) void kphase1(const float* __restrict__ tm, const int* __restrict__ adj,
                                               const float* __restrict__ part, us* __restrict__ TWb,
                                               const us* __restrict__ node0b, const us* __restrict__ Wt,
                                               const float* __restrict__ ga, us* __restrict__ Ht1,
                                               float* __restrict__ es1, float* __restrict__ ed1) {
    __shared__ __align__(16) us sm[4 * 4608];
    int bx = blockIdx.x, t = threadIdx.x;
    if (bx < 2048) {
        float* red = (float*)sm;
        float m = fmaxf(fmaxf(part[t * 4], part[t * 4 + 1]), fmaxf(part[t * 4 + 2], part[t * 4 + 3]));
        red[t] = m; __syncthreads();
        for (int s = 128; s > 0; s >>= 1) { if (t < s) red[t] = fmaxf(red[t], red[t + s]); __syncthreads(); }
        float tmx = red[0];
        #pragma unroll
        for (int it = 0; it < 4; it++) {
            size_t idx = (((size_t)bx * 4 + it) * 256 + t) * 4;
            float4 tv = *(const float4*)(tm + idx);
            int4 av = *(const int4*)(adj + idx);
            unsigned int r0 = av.x ? f2bf(__expf(0.1f * (tv.x - tmx))) : 0u;
            unsigned int r1 = av.y ? f2bf(__expf(0.1f * (tv.y - tmx))) : 0u;
            unsigned int r2 = av.z ? f2bf(__expf(0.1f * (tv.z - tmx))) : 0u;
            unsigned int r3 = av.w ? f2bf(__expf(0.1f * (tv.w - tmx))) : 0u;
            uint2 pk; pk.x = r0 | (r1 << 16); pk.y = r2 | (r3 << 16);
            *(uint2*)&TWb[idx] = pk;
        }
    } else {
        int g = bx - 2048;
        gemm_body(node0b, Wt, ga, Ht1, nullptr, es1, ed1, g & 15, 0, g >> 4, t, sm);
    }
}

// ============ layer-2 GEMM =============================================================
__global__ __launch_bounds__(256) void kgemm2(const us* __restrict__ node1b, const us* __restrict__ Wt2,
                                              const float* __restrict__ ga2, us* __restrict__ H2b,
                                              float* __restrict__ es2, float* __restrict__ ed2) {
    __shared__ __align__(16) us sm[4 * 4608];
    int x = blockIdx.x;
    gemm_body(node1b, Wt2, ga2, nullptr, H2b, es2, ed2, x & 15, x >> 4, blockIdx.y, threadIdx.x, sm);
}

// ============ layer-1 fused attention: BK=64, double-buffered, perm-packed P ============
__device__ __forceinline__ void p_tile(const us* __restrict__ twp, const float* __restrict__ edp,
                                       const us* __restrict__ htp, float es_i, float& lp,
                                       uint4& P0, uint4& P1, uint4& H0, uint4& H1) {
    union { uint4 v; us u[8]; } tw0, tw1;
    tw0.v = *(const uint4*)twp;
    tw1.v = *(const uint4*)(twp + 8);
    H0 = *(const uint4*)htp;
    H1 = *(const uint4*)(htp + 8);
    float ev[16];
    *(float4*)&ev[0]  = *(const float4*)edp;
    *(float4*)&ev[4]  = *(const float4*)(edp + 4);
    *(float4*)&ev[8]  = *(const float4*)(edp + 8);
    *(float4*)&ev[12] = *(const float4*)(edp + 12);
    unsigned int pk[8];
    #pragma unroll
    for (int r = 0; r < 4; r++) {
        float twa = bf2f(tw0.u[2 * r]), twb = bf2f(tw0.u[2 * r + 1]);
        float ea = es_i + ev[2 * r];     ea = fmaxf(ea, 0.2f * ea) * twa;
        float pa = tw0.u[2 * r] ? __expf(ea) : 0.f;
        float eb = es_i + ev[2 * r + 1]; eb = fmaxf(eb, 0.2f * eb) * twb;
        float pb = tw0.u[2 * r + 1] ? __expf(eb) : 0.f;
        lp += __uint_as_float(__float_as_uint(pa) & 0xFFFF0000u)
            + __uint_as_float(__float_as_uint(pb) & 0xFFFF0000u);
        pk[r] = __builtin_amdgcn_perm(__float_as_uint(pb), __float_as_uint(pa), 0x07060302);
    }
    #pragma unroll
    for (int r = 0; r < 4; r++) {
        float twa = bf2f(tw1.u[2 * r]), twb = bf2f(tw1.u[2 * r + 1]);
        float ea = es_i + ev[8 + 2 * r];     ea = fmaxf(ea, 0.2f * ea) * twa;
        float pa = tw1.u[2 * r] ? __expf(ea) : 0.f;
        float eb = es_i + ev[8 + 2 * r + 1]; eb = fmaxf(eb, 0.2f * eb) * twb;
        float pb = tw1.u[2 * r + 1] ? __expf(eb) : 0.f;
        lp += __uint_as_float(__float_as_uint(pa) & 0xFFFF0000u)
            + __uint_as_float(__float_as_uint(pb) & 0xFFFF0000u);
        pk[4 + r] = __builtin_amdgcn_perm(__float_as_uint(pb), __float_as_uint(pa), 0x07060302);
    }
    P0 = make_uint4(pk[0], pk[1], pk[2], pk[3]);
    P1 = make_uint4(pk[4], pk[5], pk[6], pk[7]);
}

__global__ __launch_bounds__(256) void kattn1(const us* __restrict__ TWb, const us* __restrict__ Ht,
                                              const float* __restrict__ es, const float* __restrict__ ed,
                                              us* __restrict__ node1b) {
    int x = blockIdx.x; int iblk = x & 15; int b = x >> 4; int h = blockIdx.y;
    int t = threadIdx.x;
    __shared__ __align__(16) us Ps[2 * 4608];
    __shared__ __align__(16) us Hs[2 * 4608];
    __shared__ float Ls[64 * 5];
    __shared__ float invl_s[64];
    int i = t >> 2, js = t & 3;
    int l = t & 63, w = t >> 6, m = l & 15, q = l >> 4;
    float es_i = es[h * NT + iblk * 64 + i];
    const us* twrow = TWb + ((size_t)(b * NT) + iblk * 64 + i) * NT + js * 16;
    const float* edh = ed + h * NT + js * 16;
    const us* htrow = Ht + ((size_t)(h * HD) + i) * NT + js * 16;
    f32x4 acc[4];
    #pragma unroll
    for (int ot = 0; ot < 4; ot++) acc[ot] = (f32x4){0.f, 0.f, 0.f, 0.f};
    float lp = 0.f;
    uint4 P0, P1, H0, H1;
    p_tile(twrow, edh, htrow, es_i, lp, P0, P1, H0, H1);
    {
        us* Pd = Ps + i * 72 + js * 16;
        us* Hd = Hs + i * 72 + js * 16;
        *(uint4*)Pd = P0; *(uint4*)(Pd + 8) = P1;
        *(uint4*)Hd = H0; *(uint4*)(Hd + 8) = H1;
    }
    for (int it = 0; it < 16; it++) {
        int cur = it & 1;
        if (it < 15) {
            int j0 = (it + 1) * 64;
            p_tile(twrow + j0, edh + j0, htrow + j0, es_i, lp, P0, P1, H0, H1);
        }
        __syncthreads();
        if (it < 15) {
            int nxt = cur ^ 1;
            us* Pd = Ps + nxt * 4608 + i * 72 + js * 16;
            us* Hd = Hs + nxt * 4608 + i * 72 + js * 16;
            *(uint4*)Pd = P0; *(uint4*)(Pd + 8) = P1;
            *(uint4*)Hd = H0; *(uint4*)(Hd + 8) = H1;
        }
        const us* Pc = Ps + cur * 4608; const us* Hc = Hs + cur * 4608;
        #pragma unroll
        for (int kt = 0; kt < 2; kt++) {
            bf16x8 av = *(const bf16x8*)&Pc[(w * 16 + m) * 72 + kt * 32 + q * 8];
            #pragma unroll
            for (int ot = 0; ot < 4; ot++) {
                bf16x8 bv = *(const bf16x8*)&Hc[(ot * 16 + m) * 72 + kt * 32 + q * 8];
                acc[ot] = __builtin_amdgcn_mfma_f32_16x16x32_bf16(av, bv, acc[ot], 0, 0, 0);
            }
        }
    }
    Ls[i * 5 + js] = lp;
    __syncthreads();
    if (t < 64) {
        float s = Ls[t * 5] + Ls[t * 5 + 1] + Ls[t * 5 + 2] + Ls[t * 5 + 3];
        invl_s[t] = 1.f / s;
    }
    __syncthreads();
    #pragma unroll
    for (int ot = 0; ot < 4; ot++) {
        int col = h * HD + ot * 16 + m;
        #pragma unroll
        for (int rr = 0; rr < 4; rr++) {
            int i_loc = w * 16 + q * 4 + rr;
            float v = acc[ot][rr] * invl_s[i_loc];
            v = v > 0.f ? v : (__expf(v) - 1.f);  // ELU
            node1b[(size_t)(b * NT + iblk * 64 + i_loc) * HID + col] = f2bf(v);
        }
    }
}

// ============ layer-2 attention phase A: partial PV over 64-j slices (1024 blocks) ======
__global__ __launch_bounds__(256) void kattn2a(const us* __restrict__ TWb, const us* __restrict__ H2b,
                                               const float* __restrict__ es2, const float* __restrict__ ed2,
                                               const int* __restrict__ topic_ids,
                                               float* __restrict__ ppv, float* __restrict__ pl) {
    int js = blockIdx.x, h = blockIdx.y, b = blockIdx.z;
    int t = threadIdx.x;
    __shared__ float pls[64];
    __shared__ float red[256];
    int qi = topic_ids[b];
    if (t < 64) {
        int j = js * 64 + t;
        float esq = es2[((size_t)b * NH + h) * NT + qi];
        us twu = TWb[((size_t)(b * NT) + qi) * NT + j];
        float tw = bf2f(twu);
        float e = esq + ed2[((size_t)b * NH + h) * NT + j];
        e = fmaxf(e, 0.2f * e) * tw;
        float p = twu ? __expf(e) : 0.f;
        pls[t] = p;
        float lsum = p;
        #pragma unroll
        for (int mask = 1; mask < 64; mask <<= 1) lsum += __shfl_xor(lsum, mask);
        if (t == 0) pl[((size_t)b * NH + h) * 16 + js] = lsum;
    }
    __syncthreads();
    int o = t & 63, jg = t >> 6;
    float acc = 0.f;
    const us* hb = H2b + ((size_t)(b * NT) + js * 64 + jg * 16) * HID + h * HD + o;
    #pragma unroll
    for (int jj = 0; jj < 16; jj++)
        acc = fmaf(pls[jg * 16 + jj], bf2f(hb[(size_t)jj * HID]), acc);
    red[t] = acc; __syncthreads();
    if (t < 64) {
        float pv = red[t] + red[t + 64] + red[t + 128] + red[t + 192];
        ppv[(((size_t)b * NH + h) * 16 + js) * HD + t] = pv;
    }
}

// ============ final head: reduce partials -> ELU -> combined -> fc1 relu -> fc2 =========
__global__ __launch_bounds__(256) void khead(const float* __restrict__ ppv, const float* __restrict__ pl,
                                             const float* __restrict__ attr,
                                             const float* __restrict__ aW, const float* __restrict__ ab,
                                             const float* __restrict__ fc1W, const float* __restrict__ fc1b,
                                             const float* __restrict__ fc2W, const float* __restrict__ fc2b,
                                             float* __restrict__ out) {
    int b = blockIdx.x, t = threadIdx.x;
    __shared__ float comb[HID];
    __shared__ float red[256];
    __shared__ float linv[NH];
    if (t < NH) {
        float lsum = 0.f;
        #pragma unroll
        for (int js = 0; js < 16; js++) lsum += pl[((size_t)b * NH + t) * 16 + js];
        linv[t] = 1.f / lsum;
    }
    __syncthreads();
    float av = attr[b];
    for (int k = t; k < HID; k += 256) {
        int h = k >> 6, o = k & 63;
        float pv = 0.f;
        #pragma unroll
        for (int js = 0; js < 16; js++) pv += ppv[(((size_t)b * NH + h) * 16 + js) * HD + o];
        float v = pv * linv[h];
        v = v > 0.f ? v : (__expf(v) - 1.f);  // ELU
        comb[k] = v + av * aW[k] + ab[k];
    }
    __syncthreads();
    float part = 0.f;
    for (int k = t; k < HID; k += 256) {
        const float4* wr = (const float4*)(fc1W + (size_t)k * HID);
        float acc = 0.f;
        #pragma unroll 4
        for (int mm = 0; mm < HID / 4; mm++) {
            float4 w4 = wr[mm];
            float4 c4 = *(const float4*)(comb + mm * 4);
            acc += w4.x * c4.x + w4.y * c4.y + w4.z * c4.z + w4.w * c4.w;
        }
        float hk = fmaxf(acc + fc1b[k], 0.f);
        part = fmaf(hk, fc2W[k], part);
    }
    red[t] = part; __syncthreads();
    for (int s = 128; s > 0; s >>= 1) { if (t < s) red[t] += red[t + s]; __syncthreads(); }
    if (t == 0) out[b] = red[0] + fc2b[0];
}

extern "C" void kernel_launch(void* const* d_in, const int* in_sizes, int n_in,
                              void* d_out, int out_size, void* d_ws, size_t ws_size,
                              hipStream_t stream) {
    const int*   topic_ids = (const int*)d_in[0];
    const int*   adj       = (const int*)d_in[1];
    const float* tm        = (const float*)d_in[2];
    const float* attr      = (const float*)d_in[3];
    const float* emb       = (const float*)d_in[4];
    const float* sW        = (const float*)d_in[5];
    const float* sb        = (const float*)d_in[6];
    const float* aW        = (const float*)d_in[7];
    const float* ab        = (const float*)d_in[8];
    const float* gW        = (const float*)d_in[9];   // (2,8,512,64)
    const float* ga        = (const float*)d_in[10];  // (2,8,128,1)
    const float* fc1W      = (const float*)d_in[11];
    const float* fc1b      = (const float*)d_in[12];
    const float* fc2W      = (const float*)d_in[13];
    const float* fc2b      = (const float*)d_in[14];
    float* out = (float*)d_out;

    char* p = (char*)d_ws;
    us* TWb    = (us*)p; p += sizeof(us) * (size_t)NB * NT * NT;        // 16.8 MB
    us* node0b = (us*)p; p += sizeof(us) * (size_t)NT * HID;            // 1 MB
    us* Wt     = (us*)p; p += sizeof(us) * (size_t)2 * NH * HD * HID;   // 1 MB
    us* Ht1    = (us*)p; p += sizeof(us) * (size_t)HID * NT;            // 1 MB
    us* node1b = (us*)p; p += sizeof(us) * (size_t)NB * NT * HID;       // 8 MB
    us* H2b    = (us*)p; p += sizeof(us) * (size_t)NB * NT * HID;       // 8 MB
    float* es1  = (float*)p; p += sizeof(float) * NH * NT;
    float* ed1  = (float*)p; p += sizeof(float) * NH * NT;
    float* es2  = (float*)p; p += sizeof(float) * NB * NH * NT;
    float* ed2  = (float*)p; p += sizeof(float) * NB * NH * NT;
    float* ppv  = (float*)p; p += sizeof(float) * NB * NH * 16 * HD;
    float* pl   = (float*)p; p += sizeof(float) * NB * NH * 16;
    float* part = (float*)p; p += sizeof(float) * 1024;

    kprep<<<2176, 256, 0, stream>>>(tm, part, emb, sW, sb, node0b, gW, Wt);
    kphase1<<<2176, 256, 0, stream>>>(tm, adj, part, TWb, node0b, Wt, ga, Ht1, es1, ed1);
    kattn1<<<dim3(16 * NB, NH), 256, 0, stream>>>(TWb, Ht1, es1, ed1, node1b);
    kgemm2<<<dim3(16 * NB, NH), 256, 0, stream>>>(node1b, Wt + (size_t)NH * HD * HID,
                                                  ga + NH * 2 * HD, H2b, es2, ed2);
    kattn2a<<<dim3(16, NH, NB), 256, 0, stream>>>(TWb, H2b, es2, ed2, topic_ids, ppv, pl);
    khead<<<NB, 256, 0, stream>>>(ppv, pl, attr, aW, ab, fc1W, fc1b, fc2W, fc2b, out);
}